// Round 1
// baseline (252.002 us; speedup 1.0000x reference)
//
#include <hip/hip_runtime.h>
#include <hip/hip_bf16.h>
#include <stdint.h>
#include <stddef.h>

#define N_    4096
#define C_    1000
#define CP    1024
#define A_    64
#define KPACK 2080        // 64*65/2 packed upper-triangular
#define KCROSS (KPACK + 64)   // 2144
#define KTOT  2176        // padded to multiple of 64

typedef __bf16 bf16_8 __attribute__((ext_vector_type(8)));
typedef float  f32_4  __attribute__((ext_vector_type(4)));

__device__ __forceinline__ void gl2lds16(const void* g, void* l) {
#if __has_builtin(__builtin_amdgcn_global_load_lds)
  __builtin_amdgcn_global_load_lds(
      (const __attribute__((address_space(1))) void*)g,
      (__attribute__((address_space(3))) void*)l, 16, 0, 0);
#else
  // fallback: plain 16B copy through registers
  *(int4*)l = *(const int4*)g;
#endif
}

// ---------------- prep_B: Bo[c, k] (bf16) + w2[c] ----------------
// Bo row: k<2080 -> w[a]*w[b] (packed pairs a<=b); k in [2080,2144) -> w[a]; pad 0.
__global__ void prep_b(const float* __restrict__ W, __bf16* __restrict__ Bo,
                       float* __restrict__ w2) {
  __shared__ float ws[64];
  __shared__ uint16_t pr[KPACK];
  int c = blockIdx.x;
  int t = threadIdx.x;   // 64 threads
  {
    int a = t;
    int off = a * (129 - a) / 2;
    for (int j = 0; j < 64 - a; ++j) pr[off + j] = (uint16_t)(a * 64 + a + j);
  }
  float w = 0.f;
  if (c < C_) w = W[c * 64 + t];
  ws[t] = w;
  __syncthreads();
  float s = w * w;
  for (int o = 32; o; o >>= 1) s += __shfl_down(s, o);
  if (t == 0 && c < C_) w2[c] = s;
  __bf16* row = Bo + (size_t)c * KTOT;
  for (int k = t; k < KPACK; k += 64) {
    int ab = pr[k];
    int a = ab >> 6, b = ab & 63;
    row[k] = (__bf16)(ws[a] * ws[b]);
  }
  row[KPACK + t] = (__bf16)w;
  if (t < 32) row[KCROSS + t] = (__bf16)0.f;
}

// ---------------- prep_A: Aq[n, k] (bf16) + q[n] ----------------
// Aq row: k<2080 -> (a==b ? M[a,a] : M[a,b]+M[b,a]); [2080,2144) -> -u[a]; pad 0.
// q[n] = wk^T M wk = 0.5 * wk . u
__global__ void prep_a(const float* __restrict__ W, const int* __restrict__ tgt,
                       const float* __restrict__ CV, __bf16* __restrict__ Aq,
                       float* __restrict__ qn) {
  __shared__ float Ms[64 * 65];   // stride-65 pad: 2-way bank aliasing only
  __shared__ float wk[64];
  __shared__ float us[64];
  __shared__ uint16_t pr[KPACK];
  int n = blockIdx.x;
  int t = threadIdx.x;  // 256 threads
  if (t < 64) {
    int a = t;
    int off = a * (129 - a) / 2;
    for (int j = 0; j < 64 - a; ++j) pr[off + j] = (uint16_t)(a * 64 + a + j);
  }
  int lbl = tgt[n];
  if (t < 64) wk[t] = W[lbl * 64 + t];
  const float* M = CV + (size_t)n * 4096;
  for (int i = t; i < 4096; i += 256) Ms[(i >> 6) * 65 + (i & 63)] = M[i];
  __syncthreads();
  if (t < 64) {
    int a = t;
    float acc = 0.f;
    for (int b = 0; b < 64; ++b) acc += (Ms[a * 65 + b] + Ms[b * 65 + a]) * wk[b];
    us[a] = acc;
  }
  __syncthreads();
  if (t < 64) {
    float p = wk[t] * us[t];
    for (int o = 32; o; o >>= 1) p += __shfl_down(p, o);
    if (t == 0) qn[n] = 0.5f * p;
  }
  __bf16* row = Aq + (size_t)n * KTOT;
  for (int k = t; k < KPACK; k += 256) {
    int ab = pr[k];
    int a = ab >> 6, b = ab & 63;
    float v = (a == b) ? Ms[a * 65 + a] : (Ms[a * 65 + b] + Ms[b * 65 + a]);
    row[k] = (__bf16)v;
  }
  if (t < 64) row[KPACK + t] = (__bf16)(-us[t]);
  if (t >= 64 && t < 96) row[KCROSS + (t - 64)] = (__bf16)0.f;
}

// ---------------- GEMM: S[n,c] = sum_k Aq[n,k]*Bo[c,k] ----------------
// BM=128, BN=64, BK=64; 256 threads = 4 waves; wave tile 64x32 (4x2 of 16x16).
#define BM 128
#define BN 64
#define BK 64
__global__ __launch_bounds__(256) void gemm_s(const __bf16* __restrict__ Aq,
                                              const __bf16* __restrict__ Bo,
                                              float* __restrict__ S) {
  __shared__ __bf16 As[BM * BK];   // 16 KB
  __shared__ __bf16 Bs[BN * BK];   // 8 KB
  int t = threadIdx.x;
  int lane = t & 63;
  int w = t >> 6;
  int wr = w & 1;        // row half: 0/1 -> rows [wr*64, +64)
  int wc = w >> 1;       // col half: 0/1 -> cols [wc*32, +32)
  int rowBase = blockIdx.y * BM;
  int colBase = blockIdx.x * BN;

  f32_4 acc[4][2];
  for (int mi = 0; mi < 4; ++mi)
    for (int ni = 0; ni < 2; ++ni)
      acc[mi][ni] = (f32_4){0.f, 0.f, 0.f, 0.f};

  int m0 = lane & 15;
  int q8 = (lane >> 4) * 8;

  for (int k0 = 0; k0 < KTOT; k0 += BK) {
    __syncthreads();   // protect LDS from previous iter's readers
    // stage A: 128x64 bf16 = 1024 chunks of 16B; 4 rounds x 256 threads
    for (int r = 0; r < 4; ++r) {
      int ch = r * 256 + t;
      const __bf16* g = Aq + (size_t)(rowBase + (ch >> 3)) * KTOT + k0 + ((ch & 7) << 3);
      gl2lds16(g, As + ch * 8);
    }
    // stage B: 64x64 bf16 = 512 chunks; 2 rounds
    for (int r = 0; r < 2; ++r) {
      int ch = r * 256 + t;
      const __bf16* g = Bo + (size_t)(colBase + (ch >> 3)) * KTOT + k0 + ((ch & 7) << 3);
      gl2lds16(g, Bs + ch * 8);
    }
    __syncthreads();   // staging complete (compiler drains vmcnt before barrier)
    for (int kk = 0; kk < BK; kk += 32) {
      bf16_8 af[4], bf[2];
      for (int mi = 0; mi < 4; ++mi)
        af[mi] = *(const bf16_8*)&As[(wr * 64 + mi * 16 + m0) * BK + kk + q8];
      for (int ni = 0; ni < 2; ++ni)
        bf[ni] = *(const bf16_8*)&Bs[(wc * 32 + ni * 16 + m0) * BK + kk + q8];
      for (int mi = 0; mi < 4; ++mi)
        for (int ni = 0; ni < 2; ++ni)
          acc[mi][ni] = __builtin_amdgcn_mfma_f32_16x16x32_bf16(af[mi], bf[ni], acc[mi][ni], 0, 0, 0);
    }
  }

  // C/D layout: col = lane&15, row = (lane>>4)*4 + reg  [verified m89/m91]
  int ccol = lane & 15;
  int rrow = (lane >> 4) * 4;
  for (int mi = 0; mi < 4; ++mi)
    for (int ni = 0; ni < 2; ++ni) {
      int r0 = rowBase + wr * 64 + mi * 16 + rrow;
      int c0 = colBase + wc * 32 + ni * 16 + ccol;
      for (int j = 0; j < 4; ++j)
        S[(size_t)(r0 + j) * CP + c0] = acc[mi][ni][j];
    }
}

// ---------------- epilogue: logits -> softmax -> mean NLL ----------------
__global__ void epilogue(const float* __restrict__ S, const float* __restrict__ y,
                         const float* __restrict__ w2, const float* __restrict__ qn,
                         const int* __restrict__ tgt, const float* __restrict__ ratio_p,
                         float* __restrict__ out) {
  __shared__ float red[256];
  __shared__ float lt_s;
  int n = blockIdx.x, t = threadIdx.x;
  float ratio = *ratio_p;
  int lbl = tgt[n];
  float q = qn[n];
  float w2k = w2[lbl];
  const float* Sr = S + (size_t)n * CP;
  const float* yr = y + (size_t)n * C_;
  float l[4];
  float mx = -1e30f;
  for (int i = 0; i < 4; ++i) {
    int c = t + i * 256;
    float v = -1e30f;
    if (c < C_) {
      v = yr[c] + (w2[c] - w2k) + 0.5f * ratio * (Sr[c] + q);
      if (c == lbl) lt_s = v;
    }
    l[i] = v;
    mx = fmaxf(mx, v);
  }
  red[t] = mx;
  __syncthreads();
  for (int s = 128; s; s >>= 1) {
    if (t < s) red[t] = fmaxf(red[t], red[t + s]);
    __syncthreads();
  }
  mx = red[0];
  __syncthreads();
  float se = 0.f;
  for (int i = 0; i < 4; ++i)
    if (t + i * 256 < C_) se += expf(l[i] - mx);
  red[t] = se;
  __syncthreads();
  for (int s = 128; s; s >>= 1) {
    if (t < s) red[t] += red[t + s];
    __syncthreads();
  }
  if (t == 0) {
    float lse = mx + logf(red[0]);
    float nll = lse - lt_s;
    atomicAdd(out, nll * (1.0f / (float)N_));
  }
}

extern "C" void kernel_launch(void* const* d_in, const int* in_sizes, int n_in,
                              void* d_out, int out_size, void* d_ws, size_t ws_size,
                              hipStream_t stream) {
  const float* W     = (const float*)d_in[0];   // (C, A)
  const float* y     = (const float*)d_in[1];   // (N, C)
  const int*   tgt   = (const int*)d_in[3];     // (N,)
  const float* ratio = (const float*)d_in[4];   // scalar
  const float* CV    = (const float*)d_in[5];   // (N, A, A)

  char* ws = (char*)d_ws;
  size_t off = 0;
  __bf16* Aq = (__bf16*)(ws + off); off += (size_t)N_ * KTOT * sizeof(__bf16);
  __bf16* Bo = (__bf16*)(ws + off); off += (size_t)CP * KTOT * sizeof(__bf16);
  float*  S  = (float*)(ws + off);  off += (size_t)N_ * CP * sizeof(float);
  float*  w2 = (float*)(ws + off);  off += 4096;
  float*  qn = (float*)(ws + off);  off += (size_t)N_ * sizeof(float);

  float* out = (float*)d_out;
  hipMemsetAsync(out, 0, sizeof(float), stream);                               // loss accumulator
  hipMemcpyAsync(out + 1, y, (size_t)N_ * C_ * sizeof(float),
                 hipMemcpyDeviceToDevice, stream);                             // second output = y

  prep_b<<<CP, 64, 0, stream>>>(W, Bo, w2);
  prep_a<<<N_, 256, 0, stream>>>(W, tgt, CV, Aq, qn);
  gemm_s<<<dim3(CP / BN, N_ / BM), 256, 0, stream>>>(Aq, Bo, S);
  epilogue<<<N_, 256, 0, stream>>>(S, y, w2, qn, tgt, ratio, out);
}

// Round 2
// 202.879 us; speedup vs baseline: 1.2421x; 1.2421x over previous
//
#include <hip/hip_runtime.h>
#include <hip/hip_bf16.h>
#include <stdint.h>
#include <stddef.h>

#define N_    4096
#define C_    1000
#define CP    1024
#define A_    64
#define KPACK 2080            // 64*65/2 packed upper-triangular
#define KCROSS (KPACK + 64)   // 2144
#define KTOT  2176            // padded to multiple of 64
#define KHALF 1088            // K-split half (17 blocks of 64)

typedef __bf16 bf16_2 __attribute__((ext_vector_type(2)));
typedef __bf16 bf16_8 __attribute__((ext_vector_type(8)));
typedef float  f32_4  __attribute__((ext_vector_type(4)));

__device__ __forceinline__ void gl2lds16(const void* g, void* l) {
  __builtin_amdgcn_global_load_lds(
      (const __attribute__((address_space(1))) void*)g,
      (__attribute__((address_space(3))) void*)l, 16, 0, 0);
}

// ---------------- prep_B: Bo[c, k] (bf16) + w2[c] ----------------
__global__ void prep_b(const float* __restrict__ W, __bf16* __restrict__ Bo,
                       float* __restrict__ w2) {
  __shared__ float ws[64];
  __shared__ uint16_t pr[KPACK];
  int c = blockIdx.x;
  int t = threadIdx.x;   // 64 threads
  {
    int a = t;
    int off = a * (129 - a) / 2;
    for (int j = 0; j < 64 - a; ++j) pr[off + j] = (uint16_t)(a * 64 + a + j);
  }
  float w = 0.f;
  if (c < C_) w = W[c * 64 + t];
  ws[t] = w;
  __syncthreads();
  float s = w * w;
  for (int o = 32; o; o >>= 1) s += __shfl_down(s, o);
  if (t == 0 && c < C_) w2[c] = s;
  __bf16* row = Bo + (size_t)c * KTOT;
  for (int k2 = t; k2 < KPACK / 2; k2 += 64) {     // pair-packed 4B stores
    int k = 2 * k2;
    int ab0 = pr[k], ab1 = pr[k + 1];
    bf16_2 v;
    v[0] = (__bf16)(ws[ab0 >> 6] * ws[ab0 & 63]);
    v[1] = (__bf16)(ws[ab1 >> 6] * ws[ab1 & 63]);
    *(bf16_2*)(row + k) = v;
  }
  row[KPACK + t] = (__bf16)w;
  if (t < 32) row[KCROSS + t] = (__bf16)0.f;
}

// ---------------- prep_A: Aq[n, k] (bf16) + q[n] ----------------
__global__ void prep_a(const float* __restrict__ W, const int* __restrict__ tgt,
                       const float* __restrict__ CV, __bf16* __restrict__ Aq,
                       float* __restrict__ qn) {
  __shared__ float Ms[64 * 65];
  __shared__ float wk[64];
  __shared__ float us[64];
  __shared__ uint16_t pr[KPACK];
  int n = blockIdx.x;
  int t = threadIdx.x;  // 256 threads
  if (t < 64) {
    int a = t;
    int off = a * (129 - a) / 2;
    for (int j = 0; j < 64 - a; ++j) pr[off + j] = (uint16_t)(a * 64 + a + j);
  }
  int lbl = tgt[n];
  if (t < 64) wk[t] = W[lbl * 64 + t];
  const float* M = CV + (size_t)n * 4096;
  for (int i = t; i < 4096; i += 256) Ms[(i >> 6) * 65 + (i & 63)] = M[i];
  __syncthreads();
  if (t < 64) {
    int a = t;
    float acc = 0.f;
    for (int b = 0; b < 64; ++b) acc += (Ms[a * 65 + b] + Ms[b * 65 + a]) * wk[b];
    us[a] = acc;
  }
  __syncthreads();
  if (t < 64) {
    float p = wk[t] * us[t];
    for (int o = 32; o; o >>= 1) p += __shfl_down(p, o);
    if (t == 0) qn[n] = 0.5f * p;
  }
  __bf16* row = Aq + (size_t)n * KTOT;
  for (int k2 = t; k2 < KPACK / 2; k2 += 256) {    // pair-packed 4B stores
    int k = 2 * k2;
    int ab0 = pr[k], ab1 = pr[k + 1];
    int a0 = ab0 >> 6, b0 = ab0 & 63;
    int a1 = ab1 >> 6, b1 = ab1 & 63;
    bf16_2 v;
    v[0] = (__bf16)((a0 == b0) ? Ms[a0 * 65 + a0] : (Ms[a0 * 65 + b0] + Ms[b0 * 65 + a0]));
    v[1] = (__bf16)((a1 == b1) ? Ms[a1 * 65 + a1] : (Ms[a1 * 65 + b1] + Ms[b1 * 65 + a1]));
    *(bf16_2*)(row + k) = v;
  }
  if (t < 64) row[KPACK + t] = (__bf16)(-us[t]);
  if (t >= 64 && t < 96) row[KCROSS + (t - 64)] = (__bf16)0.f;
}

// ---------------- GEMM: S[n,c] += sum_k Aq[n,k]*Bo[c,k] over [kb,ke) --------
// m97-shape: BM=BN=128, BK=64; 4 waves, each 64x64 (4x4 of 16x16x32).
#define BM 128
#define BN 128
#define BK 64
__global__ __launch_bounds__(256) void gemm_s(const __bf16* __restrict__ Aq,
                                              const __bf16* __restrict__ Bo,
                                              float* __restrict__ Sbase,
                                              int khalf) {
  __shared__ __bf16 As[BM * BK];   // 16 KB
  __shared__ __bf16 Bs[BN * BK];   // 16 KB
  int t = threadIdx.x;
  int lane = t & 63;
  int w = t >> 6;
  int wr = w & 1;        // row half of the 128x128 tile
  int wc = w >> 1;       // col half
  int rowBase = blockIdx.y * BM;
  int colBase = blockIdx.x * BN;
  int kb = blockIdx.z * khalf;
  int ke = kb + khalf;
  float* S = Sbase + (size_t)blockIdx.z * ((size_t)N_ * CP);

  f32_4 acc[4][4];
  for (int mi = 0; mi < 4; ++mi)
    for (int ni = 0; ni < 4; ++ni)
      acc[mi][ni] = (f32_4){0.f, 0.f, 0.f, 0.f};

  int m0 = lane & 15;
  int q8 = (lane >> 4) * 8;

  for (int k0 = kb; k0 < ke; k0 += BK) {
    __syncthreads();
    // stage A: 128x64 bf16 = 1024 x 16B chunks; 4 rounds x 256 threads
    for (int r = 0; r < 4; ++r) {
      int ch = r * 256 + t;
      const __bf16* g = Aq + (size_t)(rowBase + (ch >> 3)) * KTOT + k0 + ((ch & 7) << 3);
      gl2lds16(g, As + ch * 8);
    }
    // stage B: 128x64 = 1024 chunks; 4 rounds
    for (int r = 0; r < 4; ++r) {
      int ch = r * 256 + t;
      const __bf16* g = Bo + (size_t)(colBase + (ch >> 3)) * KTOT + k0 + ((ch & 7) << 3);
      gl2lds16(g, Bs + ch * 8);
    }
    __syncthreads();
    for (int kk = 0; kk < BK; kk += 32) {
      bf16_8 af[4], bf[4];
      for (int mi = 0; mi < 4; ++mi)
        af[mi] = *(const bf16_8*)&As[(wr * 64 + mi * 16 + m0) * BK + kk + q8];
      for (int ni = 0; ni < 4; ++ni)
        bf[ni] = *(const bf16_8*)&Bs[(wc * 64 + ni * 16 + m0) * BK + kk + q8];
      for (int mi = 0; mi < 4; ++mi)
        for (int ni = 0; ni < 4; ++ni)
          acc[mi][ni] = __builtin_amdgcn_mfma_f32_16x16x32_bf16(af[mi], bf[ni], acc[mi][ni], 0, 0, 0);
    }
  }

  // C/D layout: col = lane&15, row = (lane>>4)*4 + reg  [m89/m91]
  int ccol = lane & 15;
  int rrow = (lane >> 4) * 4;
  for (int mi = 0; mi < 4; ++mi)
    for (int ni = 0; ni < 4; ++ni) {
      int r0 = rowBase + wr * 64 + mi * 16 + rrow;
      int c0 = colBase + wc * 64 + ni * 16 + ccol;
      for (int j = 0; j < 4; ++j)
        S[(size_t)(r0 + j) * CP + c0] = acc[mi][ni][j];
    }
}

// ---------------- epilogue: logits -> softmax -> per-row NLL ----------------
__global__ void epilogue(const float* __restrict__ S0, const float* __restrict__ S1,
                         int split, const float* __restrict__ y,
                         const float* __restrict__ w2, const float* __restrict__ qn,
                         const int* __restrict__ tgt, const float* __restrict__ ratio_p,
                         float* __restrict__ nll) {
  __shared__ float red[256];
  __shared__ float lt_s;
  int n = blockIdx.x, t = threadIdx.x;
  float hr = 0.5f * (*ratio_p);
  int lbl = tgt[n];
  float q = qn[n];
  float w2k = w2[lbl];
  const float* Sr0 = S0 + (size_t)n * CP;
  const float* Sr1 = S1 + (size_t)n * CP;
  const float* yr = y + (size_t)n * C_;
  float l[4];
  float mx = -1e30f;
  for (int i = 0; i < 4; ++i) {
    int c = t + i * 256;
    float v = -1e30f;
    if (c < C_) {
      float s = Sr0[c] + (split ? Sr1[c] : 0.f);
      v = yr[c] + (w2[c] - w2k) + hr * (s + q);
      if (c == lbl) lt_s = v;
    }
    l[i] = v;
    mx = fmaxf(mx, v);
  }
  red[t] = mx;
  __syncthreads();
  for (int s = 128; s; s >>= 1) {
    if (t < s) red[t] = fmaxf(red[t], red[t + s]);
    __syncthreads();
  }
  mx = red[0];
  __syncthreads();
  float se = 0.f;
  for (int i = 0; i < 4; ++i)
    if (t + i * 256 < C_) se += expf(l[i] - mx);
  red[t] = se;
  __syncthreads();
  for (int s = 128; s; s >>= 1) {
    if (t < s) red[t] += red[t + s];
    __syncthreads();
  }
  if (t == 0) nll[n] = (mx + logf(red[0])) - lt_s;
}

// ---------------- final mean reduction (no atomics) ----------------
__global__ void reduce_loss(const float* __restrict__ nll, float* __restrict__ out) {
  int t = threadIdx.x;  // 256
  float s = 0.f;
  for (int i = t; i < N_; i += 256) s += nll[i];
  for (int o = 32; o; o >>= 1) s += __shfl_down(s, o);
  __shared__ float r[4];
  if ((t & 63) == 0) r[t >> 6] = s;
  __syncthreads();
  if (t == 0) out[0] = (r[0] + r[1] + r[2] + r[3]) * (1.0f / (float)N_);
}

extern "C" void kernel_launch(void* const* d_in, const int* in_sizes, int n_in,
                              void* d_out, int out_size, void* d_ws, size_t ws_size,
                              hipStream_t stream) {
  const float* W     = (const float*)d_in[0];   // (C, A)
  const float* y     = (const float*)d_in[1];   // (N, C)
  const int*   tgt   = (const int*)d_in[3];     // (N,)
  const float* ratio = (const float*)d_in[4];   // scalar
  const float* CV    = (const float*)d_in[5];   // (N, A, A)

  char* ws = (char*)d_ws;
  size_t off = 0;
  __bf16* Aq = (__bf16*)(ws + off); off += (size_t)N_ * KTOT * sizeof(__bf16);
  __bf16* Bo = (__bf16*)(ws + off); off += (size_t)CP * KTOT * sizeof(__bf16);
  float*  S0 = (float*)(ws + off);  off += (size_t)N_ * CP * sizeof(float);
  size_t off_nosplit = off;         // S1 only exists in split mode
  float*  S1 = (float*)(ws + off);
  size_t off_split = off + (size_t)N_ * CP * sizeof(float);

  // choose K-split (2 blocks/CU) iff workspace allows the second S buffer
  size_t tail = 4096 + (size_t)N_ * sizeof(float) * 2;
  int split = (ws_size >= off_split + tail) ? 1 : 0;
  off = split ? off_split : off_nosplit;
  float* w2  = (float*)(ws + off);  off += 4096;
  float* qn  = (float*)(ws + off);  off += (size_t)N_ * sizeof(float);
  float* nll = (float*)(ws + off);  off += (size_t)N_ * sizeof(float);

  float* out = (float*)d_out;
  hipMemcpyAsync(out + 1, y, (size_t)N_ * C_ * sizeof(float),
                 hipMemcpyDeviceToDevice, stream);   // second output = y verbatim

  prep_b<<<CP, 64, 0, stream>>>(W, Bo, w2);
  prep_a<<<N_, 256, 0, stream>>>(W, tgt, CV, Aq, qn);
  if (split)
    gemm_s<<<dim3(CP / BN, N_ / BM, 2), 256, 0, stream>>>(Aq, Bo, S0, KHALF);
  else
    gemm_s<<<dim3(CP / BN, N_ / BM, 1), 256, 0, stream>>>(Aq, Bo, S0, KTOT);
  epilogue<<<N_, 256, 0, stream>>>(S0, S1, split, y, w2, qn, tgt, ratio, nll);
  reduce_loss<<<1, 256, 0, stream>>>(nll, out);
}

// Round 3
// 182.041 us; speedup vs baseline: 1.3843x; 1.1145x over previous
//
#include <hip/hip_runtime.h>
#include <hip/hip_bf16.h>
#include <stdint.h>
#include <stddef.h>

#define N_    4096
#define C_    1000
#define CP    1024
#define A_    64
#define KPACK 2080            // 64*65/2 packed upper-triangular
#define KCROSS (KPACK + 64)   // 2144
#define KTOT  2176            // padded to multiple of 64
#define KHALF 1088            // K-split half
#define MS    68              // LDS row stride for M (16B-aligned, odd-bank-ish)

typedef __bf16 bf16_2 __attribute__((ext_vector_type(2)));
typedef __bf16 bf16_8 __attribute__((ext_vector_type(8)));
typedef float  f32_4  __attribute__((ext_vector_type(4)));

__device__ __forceinline__ void gl2lds16(const void* g, void* l) {
  __builtin_amdgcn_global_load_lds(
      (const __attribute__((address_space(1))) void*)g,
      (__attribute__((address_space(3))) void*)l, 16, 0, 0);
}

// unpack packed upper-tri index k -> (a,b), a<=b.  off(a)=a*(129-a)/2
__device__ __forceinline__ void unpack_pair(int k, int& a, int& b) {
  a = (int)(0.5f * (129.0f - sqrtf((float)(16641 - 8 * k))));
  if (a < 0) a = 0;
  while ((a + 1) * (129 - (a + 1)) / 2 <= k) ++a;   // <=1 step
  while (a * (129 - a) / 2 > k) --a;                // <=1 step
  b = k - a * (129 - a) / 2 + a;
}

// ---------------- prep_all: blocks [0,1024) build Bo rows + w2;
//                  blocks [1024,5120) build Aq rows + qn ----------------
__global__ __launch_bounds__(256) void prep_all(
    const float* __restrict__ W, const int* __restrict__ tgt,
    const float* __restrict__ CV, __bf16* __restrict__ Bo,
    float* __restrict__ w2, __bf16* __restrict__ Aq, float* __restrict__ qn) {
  __shared__ float Ms[64 * MS];   // A-branch: M staging | B-branch: ws in [0,64)
  __shared__ float up[4 * 64];
  __shared__ float wk[64];
  __shared__ float us[64];
  int t = threadIdx.x;

  if (blockIdx.x < 1024) {
    // ---- B branch: row c of Bo ----
    int c = blockIdx.x;
    float* ws = Ms;
    if (t < 64) {
      float w = (c < C_) ? W[c * 64 + t] : 0.f;
      ws[t] = w;
      float s = w * w;
      for (int o = 32; o; o >>= 1) s += __shfl_down(s, o);
      if (t == 0 && c < C_) w2[c] = s;
    }
    __syncthreads();
    __bf16* row = Bo + (size_t)c * KTOT;
    for (int p = t; p < KPACK / 2; p += 256) {
      int k = 2 * p;
      int a0, b0, a1, b1;
      unpack_pair(k, a0, b0);
      if (b0 == 63) { a1 = a0 + 1; b1 = a1; } else { a1 = a0; b1 = b0 + 1; }
      bf16_2 v;
      v[0] = (__bf16)(ws[a0] * ws[b0]);
      v[1] = (__bf16)(ws[a1] * ws[b1]);
      *(bf16_2*)(row + k) = v;
    }
    if (t < 64) row[KPACK + t] = (__bf16)ws[t];
    if (t >= 64 && t < 96) row[KCROSS + (t - 64)] = (__bf16)0.f;
  } else {
    // ---- A branch: row n of Aq ----
    int n = blockIdx.x - 1024;
    int lbl = tgt[n];
    if (t < 64) wk[t] = W[lbl * 64 + t];
    const float4* M4 = (const float4*)(CV + (size_t)n * 4096);
    for (int j = 0; j < 4; ++j) {       // 1024 float4 chunks, 16B-aligned LDS rows
      int i4 = t + j * 256;
      int r = i4 >> 4, c4 = (i4 & 15) << 2;
      *(float4*)&Ms[r * MS + c4] = M4[i4];
    }
    __syncthreads();
    {   // u[a] = sum_b (M[a][b]+M[b][a]) wk[b], 256-thread parallel
      int a = t & 63, seg = t >> 6;
      float acc = 0.f;
      for (int b = seg * 16; b < seg * 16 + 16; ++b)
        acc += (Ms[a * MS + b] + Ms[b * MS + a]) * wk[b];
      up[seg * 64 + a] = acc;
    }
    __syncthreads();
    if (t < 64) {
      float u = up[t] + up[64 + t] + up[128 + t] + up[192 + t];
      us[t] = u;
      float p = wk[t] * u;
      for (int o = 32; o; o >>= 1) p += __shfl_down(p, o);
      if (t == 0) qn[n] = 0.5f * p;
    }
    __syncthreads();
    __bf16* row = Aq + (size_t)n * KTOT;
    for (int p = t; p < KPACK / 2; p += 256) {
      int k = 2 * p;
      int a0, b0, a1, b1;
      unpack_pair(k, a0, b0);
      if (b0 == 63) { a1 = a0 + 1; b1 = a1; } else { a1 = a0; b1 = b0 + 1; }
      bf16_2 v;
      v[0] = (__bf16)((a0 == b0) ? Ms[a0 * MS + a0]
                                 : (Ms[a0 * MS + b0] + Ms[b0 * MS + a0]));
      v[1] = (__bf16)((a1 == b1) ? Ms[a1 * MS + a1]
                                 : (Ms[a1 * MS + b1] + Ms[b1 * MS + a1]));
      *(bf16_2*)(row + k) = v;
    }
    if (t < 64) row[KPACK + t] = (__bf16)(-us[t]);
    if (t >= 64 && t < 96) row[KCROSS + (t - 64)] = (__bf16)0.f;
  }
}

// ---------------- GEMM: S[n,c] = sum_k Aq[n,k]*Bo[c,k], K-split via z --------
// BM=BN=128, BK=64; 4 waves x (64x64). LDS chunk-XOR swizzle kills the
// 16-way ds_read_b128 bank conflict (row stride 128B == 32 banks).
#define BM 128
#define BN 128
#define BK 64
__global__ __launch_bounds__(256) void gemm_s(const __bf16* __restrict__ Aq,
                                              const __bf16* __restrict__ Bo,
                                              float* __restrict__ Sbase,
                                              int khalf) {
  __shared__ __bf16 As[BM * BK];   // 16 KB
  __shared__ __bf16 Bs[BN * BK];   // 16 KB
  int t = threadIdx.x;
  int lane = t & 63;
  int w = t >> 6;
  int wr = w & 1;
  int wc = w >> 1;
  int rowBase = blockIdx.y * BM;
  int colBase = blockIdx.x * BN;
  int kb = blockIdx.z * khalf;
  int ke = kb + khalf;
  float* S = Sbase + (size_t)blockIdx.z * ((size_t)N_ * CP);

  f32_4 acc[4][4];
  for (int mi = 0; mi < 4; ++mi)
    for (int ni = 0; ni < 4; ++ni)
      acc[mi][ni] = (f32_4){0.f, 0.f, 0.f, 0.f};

  int m0 = lane & 15;
  int qsw = m0 & 7;            // per-lane swizzle key (row&7 == m0&7)

  for (int k0 = kb; k0 < ke; k0 += BK) {
    __syncthreads();
    // stage A: source chunk permuted so LDS phys slot = lane-linear,
    // logical chunk q_log lives at phys qp where q_log = qp ^ (row&7)
    for (int r = 0; r < 4; ++r) {
      int ch = r * 256 + t;
      int row_p = ch >> 3, qp = ch & 7;
      int q_log = qp ^ (row_p & 7);
      const __bf16* g = Aq + (size_t)(rowBase + row_p) * KTOT + k0 + (q_log << 3);
      gl2lds16(g, As + ch * 8);
    }
    for (int r = 0; r < 4; ++r) {
      int ch = r * 256 + t;
      int row_p = ch >> 3, qp = ch & 7;
      int q_log = qp ^ (row_p & 7);
      const __bf16* g = Bo + (size_t)(colBase + row_p) * KTOT + k0 + (q_log << 3);
      gl2lds16(g, Bs + ch * 8);
    }
    __syncthreads();
    for (int kk = 0; kk < BK; kk += 32) {
      int qbase = (kk >> 3) + (lane >> 4);     // logical chunk 0..7
      int qphys = qbase ^ qsw;                 // swizzled phys chunk
      bf16_8 af[4], bf[4];
      for (int mi = 0; mi < 4; ++mi)
        af[mi] = *(const bf16_8*)&As[(wr * 64 + mi * 16 + m0) * BK + (qphys << 3)];
      for (int ni = 0; ni < 4; ++ni)
        bf[ni] = *(const bf16_8*)&Bs[(wc * 64 + ni * 16 + m0) * BK + (qphys << 3)];
      for (int mi = 0; mi < 4; ++mi)
        for (int ni = 0; ni < 4; ++ni)
          acc[mi][ni] = __builtin_amdgcn_mfma_f32_16x16x32_bf16(af[mi], bf[ni], acc[mi][ni], 0, 0, 0);
    }
  }

  // C/D layout: col = lane&15, row = (lane>>4)*4 + reg  [m89/m91]
  int ccol = lane & 15;
  int rrow = (lane >> 4) * 4;
  for (int mi = 0; mi < 4; ++mi)
    for (int ni = 0; ni < 4; ++ni) {
      int r0 = rowBase + wr * 64 + mi * 16 + rrow;
      int c0 = colBase + wc * 64 + ni * 16 + ccol;
      for (int j = 0; j < 4; ++j)
        S[(size_t)(r0 + j) * CP + c0] = acc[mi][ni][j];
    }
}

// ---------------- epilogue: wave-per-row softmax -> nll[n] ----------------
__global__ __launch_bounds__(256) void epilogue(
    const float* __restrict__ S0, const float* __restrict__ S1, int split,
    const float* __restrict__ y, const float* __restrict__ w2,
    const float* __restrict__ qn, const int* __restrict__ tgt,
    const float* __restrict__ ratio_p, float* __restrict__ nll) {
  int t = threadIdx.x, lane = t & 63, w = t >> 6;
  int n = blockIdx.x * 4 + w;
  float hr = 0.5f * (*ratio_p);
  int lbl = tgt[n];
  float q = qn[n];
  float w2k = w2[lbl];
  const float4* S0r = (const float4*)(S0 + (size_t)n * CP);
  const float4* S1r = (const float4*)(S1 + (size_t)n * CP);
  const float4* w24 = (const float4*)w2;
  const float* yr = y + (size_t)n * C_;
  float l[16];
  float mx = -1e30f;
  for (int i = 0; i < 4; ++i) {
    int idx = i * 64 + lane;             // float4 index; c = idx*4+j
    float4 s0 = S0r[idx];
    float4 s1 = split ? S1r[idx] : (float4){0.f, 0.f, 0.f, 0.f};
    float4 w4 = w24[idx];
    int c = idx * 4;
    float sv[4] = {s0.x + s1.x, s0.y + s1.y, s0.z + s1.z, s0.w + s1.w};
    float wv[4] = {w4.x, w4.y, w4.z, w4.w};
    for (int j = 0; j < 4; ++j) {
      float v = -1e30f;
      if (c + j < C_)
        v = yr[c + j] + (wv[j] - w2k) + hr * (sv[j] + q);
      l[i * 4 + j] = v;
      mx = fmaxf(mx, v);
    }
  }
  for (int o = 32; o; o >>= 1) mx = fmaxf(mx, __shfl_xor(mx, o));
  float se = 0.f, lt = 0.f;
  for (int i = 0; i < 4; ++i) {
    int c = (i * 64 + lane) * 4;
    for (int j = 0; j < 4; ++j) {
      float v = l[i * 4 + j];
      se += expf(v - mx);               // -1e30 rows contribute exactly 0
      lt += (c + j == lbl) ? v : 0.f;
    }
  }
  for (int o = 32; o; o >>= 1) {
    se += __shfl_xor(se, o);
    lt += __shfl_xor(lt, o);
  }
  if (lane == 0) nll[n] = (mx + logf(se)) - lt;
}

// ---------------- final mean (single small block, no atomics) ----------------
__global__ void reduce_loss(const float* __restrict__ nll, float* __restrict__ out) {
  int t = threadIdx.x;  // 256
  float s = 0.f;
  for (int i = t; i < N_; i += 256) s += nll[i];
  for (int o = 32; o; o >>= 1) s += __shfl_down(s, o);
  __shared__ float r[4];
  if ((t & 63) == 0) r[t >> 6] = s;
  __syncthreads();
  if (t == 0) out[0] = (r[0] + r[1] + r[2] + r[3]) * (1.0f / (float)N_);
}

extern "C" void kernel_launch(void* const* d_in, const int* in_sizes, int n_in,
                              void* d_out, int out_size, void* d_ws, size_t ws_size,
                              hipStream_t stream) {
  const float* W     = (const float*)d_in[0];   // (C, A)
  const float* y     = (const float*)d_in[1];   // (N, C)
  const int*   tgt   = (const int*)d_in[3];     // (N,)
  const float* ratio = (const float*)d_in[4];   // scalar
  const float* CV    = (const float*)d_in[5];   // (N, A, A)

  char* ws = (char*)d_ws;
  size_t off = 0;
  __bf16* Aq = (__bf16*)(ws + off); off += (size_t)N_ * KTOT * sizeof(__bf16);
  __bf16* Bo = (__bf16*)(ws + off); off += (size_t)CP * KTOT * sizeof(__bf16);
  float*  S0 = (float*)(ws + off);  off += (size_t)N_ * CP * sizeof(float);
  size_t off_nosplit = off;
  float*  S1 = (float*)(ws + off);
  size_t off_split = off + (size_t)N_ * CP * sizeof(float);

  size_t tail = 4096 + (size_t)N_ * sizeof(float) * 2;
  int split = (ws_size >= off_split + tail) ? 1 : 0;
  off = split ? off_split : off_nosplit;
  float* w2  = (float*)(ws + off);  off += 4096;
  float* qn  = (float*)(ws + off);  off += (size_t)N_ * sizeof(float);
  float* nll = (float*)(ws + off);  off += (size_t)N_ * sizeof(float);

  float* out = (float*)d_out;
  hipMemcpyAsync(out + 1, y, (size_t)N_ * C_ * sizeof(float),
                 hipMemcpyDeviceToDevice, stream);   // second output = y verbatim

  prep_all<<<1024 + N_, 256, 0, stream>>>(W, tgt, CV, Bo, w2, Aq, qn);
  if (split)
    gemm_s<<<dim3(CP / BN, N_ / BM, 2), 256, 0, stream>>>(Aq, Bo, S0, KHALF);
  else
    gemm_s<<<dim3(CP / BN, N_ / BM, 1), 256, 0, stream>>>(Aq, Bo, S0, KTOT);
  epilogue<<<N_ / 4, 256, 0, stream>>>(S0, S1, split, y, w2, qn, tgt, ratio, nll);
  reduce_loss<<<1, 256, 0, stream>>>(nll, out);
}